// Round 7
// baseline (156.047 us; speedup 1.0000x reference)
//
#include <hip/hip_runtime.h>
#include <hip/hip_fp16.h>

// GraphConv: out[b,v,u] = relu( sum_{r,c} gather(nodes)[b,v,r,c] * kernel[r*C+c,u] + bias[u] )
// B=16, V=10000, R=8, C=64, U=64.  M=160000 rows, K=512, N=64.
//
// Design (round 7 = round 6 resubmitted after broker timeout; VGPR audit passed):
//  - Single kernel, no prepass (f32 gather bytes == f16 hi/lo pair bytes; prepass would
//    add ~13 us HBM). Inline f32->f16 hi/lo via v_cvt_pkrtz; VALU hides under MFMA (m114).
//  - 3-term f16 split: Ah*Bh (main acc) + Al*Bh + Ah*Bl (correction acc, lo prescaled
//    x2048 against f16 denormal flush). Residual ~1e-6 relative.
//  - mfma_f32_32x32x16_f16. A-frag row=lane&31, k=(lane>>5)*8+j; B-frag col=lane&31,
//    same k; C/D col=lane&31, row=(q&3)+8*(q>>2)+4*(lane>>5) [m74/m101-verified].
//  - B fragments (hi 64K + lo 64K = 128 KiB) staged once/block into dynamic LDS,
//    lane-contiguous 16 B stride (conflict-free ds_read_b128). 1 block/CU x 8 waves.
//  - BRANCHLESS gather: clamp mi<0 -> row 0, load unconditionally, zero the packed f16
//    words with per-lane AND masks. No divergent branch in the main loop; all 8 r's
//    addresses known at loop entry -> scheduler pipelines the 200-500 cy gather latency
//    within the 256-VGPR budget (~1-2 iterations of lookahead).
//  - Mapping preloaded (2 x int4) before LDS staging: latency hides under staging.
//  - Nontemporal output stores: 41 MB streamed once, preserve L2 for node-row reuse.
//  - b = blockIdx&15 -> round-robin XCD dispatch pins batches to XCD L2s.

#define Bn 16
#define Vn 10000
#define Rn 8
#define Cn 64
#define Un 64

#define LOSCALE 2048.0f
#define LOINV   (1.0f/2048.0f)

typedef _Float16      f16x8   __attribute__((ext_vector_type(8)));
typedef __fp16        fp16x2  __attribute__((ext_vector_type(2)));   // cvt_pkrtz return type
typedef float         f32x16  __attribute__((ext_vector_type(16)));
typedef unsigned int  u32x4   __attribute__((ext_vector_type(4)));
typedef unsigned short us8    __attribute__((ext_vector_type(8)));

__device__ __forceinline__ unsigned short f16b(_Float16 h) {
    return __builtin_bit_cast(unsigned short, h);
}

// packed f32x2 -> f16x2 (RTZ) as one u32. RTZ on hi is fine: lo captures the residual.
__device__ __forceinline__ unsigned int cvt2w(float a0, float a1) {
    const fp16x2 p = __builtin_amdgcn_cvt_pkrtz(a0, a1);
    return __builtin_bit_cast(unsigned int, p);
}
__device__ __forceinline__ _Float16 loh(unsigned int w) {   // low f16 of word
    return __builtin_bit_cast(_Float16, (unsigned short)(w & 0xffff));
}
__device__ __forceinline__ _Float16 hih(unsigned int w) {   // high f16 of word
    return __builtin_bit_cast(_Float16, (unsigned short)(w >> 16));
}

// LDS layout: fragment f in [0,64) (f = nt*32 + kt), lane l:
//   hi plane: byte f*1024 + l*16            (us8 = 8 f16)
//   lo plane: byte 65536 + f*1024 + l*16
#define LDS_LO 65536

__global__ __launch_bounds__(512, 2)
void graphconv_kernel(const float* __restrict__ nodes,
                      const int* __restrict__ mapping,
                      const float* __restrict__ kern,
                      const float* __restrict__ bias,
                      float* __restrict__ out) {
    extern __shared__ unsigned char lds[];   // 131072 B
    const int tid  = threadIdx.x;
    const int lane = tid & 63;
    const int w    = tid >> 6;               // wave 0..7
    const int g    = blockIdx.x;
    const int b    = g & 15;                 // batch; round-robin over XCDs
    const int v0   = (g >> 4) << 8;          // 256 rows per block

    const int row = lane & 31;
    const int grp = lane >> 5;               // which K-half of each fragment
    const int v   = v0 + w * 32 + row;
    const bool vok = v < Vn;

    // ---- preload this row's 8 mapping entries FIRST (latency hides under staging) ----
    int4 m03 = make_int4(-1, -1, -1, -1), m47 = make_int4(-1, -1, -1, -1);
    if (vok) {
        const int4* mp4 = (const int4*)(mapping + ((size_t)b * Vn + v) * Rn);
        m03 = mp4[0];
        m47 = mp4[1];
    }

    // ---- stage B fragments (f32 kern -> f16 hi/lo) into LDS, once ----
    #pragma unroll
    for (int it = 0; it < 8; ++it) {
        const int gg = it * 512 + tid;       // 4096 (frag,lane) groups
        const int f  = gg >> 6;              // nt*32 + kt
        const int l  = gg & 63;
        const int nt = f >> 5;
        const int kt = f & 31;
        const int n  = nt * 32 + (l & 31);
        const int kb = kt * 16 + ((l >> 5) << 3);
        us8 hh, ll;
        #pragma unroll
        for (int j = 0; j < 8; ++j) {
            const float x = kern[(kb + j) * Un + n];
            const _Float16 h  = (_Float16)x;
            const _Float16 lo = (_Float16)((x - (float)h) * LOSCALE);
            hh[j] = f16b(h);
            ll[j] = f16b(lo);
        }
        *(us8*)(lds + (size_t)f * 1024 + (size_t)l * 16)          = hh;
        *(us8*)(lds + LDS_LO + (size_t)f * 1024 + (size_t)l * 16) = ll;
    }
    __syncthreads();

    int mv[8];
    mv[0] = m03.x; mv[1] = m03.y; mv[2] = m03.z; mv[3] = m03.w;
    mv[4] = m47.x; mv[5] = m47.y; mv[6] = m47.z; mv[7] = m47.w;

    f32x16 am0 = {0,0,0,0,0,0,0,0,0,0,0,0,0,0,0,0};   // main acc, cols 0-31
    f32x16 am1 = {0,0,0,0,0,0,0,0,0,0,0,0,0,0,0,0};   // main acc, cols 32-63
    f32x16 ac0 = {0,0,0,0,0,0,0,0,0,0,0,0,0,0,0,0};   // correction acc (x LOSCALE)
    f32x16 ac1 = {0,0,0,0,0,0,0,0,0,0,0,0,0,0,0,0};

    #pragma unroll
    for (int r = 0; r < Rn; ++r) {
        const int mi   = mv[r];                          // static index after unroll
        const int idxc = (mi >= 0) ? mi : 0;             // branchless clamp (always valid)
        const unsigned int keep = (mi >= 0) ? 0xffffffffu : 0u;   // per-lane zero mask
        const float* src = nodes + ((size_t)b * Vn + idxc) * Cn;
        f16x8 ah[4], al[4];
        #pragma unroll
        for (int kk = 0; kk < 4; ++kk) {
            const int cb = kk * 16 + grp * 8;
            const float4 xa = *(const float4*)(src + cb);      // unconditional loads:
            const float4 xb = *(const float4*)(src + cb + 4);  // pipelinable across r
            u32x4 hw, lw;
            hw[0] = cvt2w(xa.x, xa.y); hw[1] = cvt2w(xa.z, xa.w);
            hw[2] = cvt2w(xb.x, xb.y); hw[3] = cvt2w(xb.z, xb.w);
            lw[0] = cvt2w((xa.x - (float)loh(hw[0])) * LOSCALE,
                          (xa.y - (float)hih(hw[0])) * LOSCALE);
            lw[1] = cvt2w((xa.z - (float)loh(hw[1])) * LOSCALE,
                          (xa.w - (float)hih(hw[1])) * LOSCALE);
            lw[2] = cvt2w((xb.x - (float)loh(hw[2])) * LOSCALE,
                          (xb.y - (float)hih(hw[2])) * LOSCALE);
            lw[3] = cvt2w((xb.z - (float)loh(hw[3])) * LOSCALE,
                          (xb.w - (float)hih(hw[3])) * LOSCALE);
            #pragma unroll
            for (int q = 0; q < 4; ++q) { hw[q] &= keep; lw[q] &= keep; }
            ah[kk] = __builtin_bit_cast(f16x8, hw);
            al[kk] = __builtin_bit_cast(f16x8, lw);
        }
        #pragma unroll
        for (int kk = 0; kk < 4; ++kk) {
            const int kt = r * 4 + kk;
            const size_t fb0 = (size_t)(kt)      * 1024 + (size_t)lane * 16;  // nt=0
            const size_t fb1 = (size_t)(32 + kt) * 1024 + (size_t)lane * 16;  // nt=1
            const f16x8 bh0 = __builtin_bit_cast(f16x8, *(const us8*)(lds + fb0));
            const f16x8 bl0 = __builtin_bit_cast(f16x8, *(const us8*)(lds + LDS_LO + fb0));
            const f16x8 bh1 = __builtin_bit_cast(f16x8, *(const us8*)(lds + fb1));
            const f16x8 bl1 = __builtin_bit_cast(f16x8, *(const us8*)(lds + LDS_LO + fb1));
            am0 = __builtin_amdgcn_mfma_f32_32x32x16_f16(ah[kk], bh0, am0, 0, 0, 0);
            ac0 = __builtin_amdgcn_mfma_f32_32x32x16_f16(al[kk], bh0, ac0, 0, 0, 0);
            ac0 = __builtin_amdgcn_mfma_f32_32x32x16_f16(ah[kk], bl0, ac0, 0, 0, 0);
            am1 = __builtin_amdgcn_mfma_f32_32x32x16_f16(ah[kk], bh1, am1, 0, 0, 0);
            ac1 = __builtin_amdgcn_mfma_f32_32x32x16_f16(al[kk], bh1, ac1, 0, 0, 0);
            ac1 = __builtin_amdgcn_mfma_f32_32x32x16_f16(ah[kk], bl1, ac1, 0, 0, 0);
        }
    }

    // ---- epilogue: combine hi/lo, bias, relu, nontemporal store ----
    const int n0    = lane & 31;
    const float bv0 = bias[n0];
    const float bv1 = bias[32 + n0];
    const int rbase = v0 + w * 32 + 4 * grp;
    #pragma unroll
    for (int q = 0; q < 16; ++q) {
        const int vv = rbase + (q & 3) + 8 * (q >> 2);
        if (vv < Vn) {
            float* o = out + ((size_t)b * Vn + vv) * Un;
            const float x0 = am0[q] + ac0[q] * LOINV + bv0;
            const float x1 = am1[q] + ac1[q] * LOINV + bv1;
            __builtin_nontemporal_store(x0 > 0.f ? x0 : 0.f, o + n0);
            __builtin_nontemporal_store(x1 > 0.f ? x1 : 0.f, o + 32 + n0);
        }
    }
}

extern "C" void kernel_launch(void* const* d_in, const int* in_sizes, int n_in,
                              void* d_out, int out_size, void* d_ws, size_t ws_size,
                              hipStream_t stream) {
    (void)in_sizes; (void)n_in; (void)out_size; (void)d_ws; (void)ws_size;
    const float* nodes   = (const float*)d_in[0];
    const int*   mapping = (const int*)d_in[1];
    const float* kern    = (const float*)d_in[2];
    const float* bias    = (const float*)d_in[3];
    float* out = (float*)d_out;

    static const int lds_bytes = 131072;
    (void)hipFuncSetAttribute(reinterpret_cast<const void*>(&graphconv_kernel),
                              hipFuncAttributeMaxDynamicSharedMemorySize, lds_bytes);
    // 16 batches x 40 v-tiles (256 rows each)
    hipLaunchKernelGGL(graphconv_kernel, dim3(16 * 40), dim3(512), lds_bytes, stream,
                       nodes, mapping, kern, bias, out);
}